// Round 1
// baseline (1455.347 us; speedup 1.0000x reference)
//
#include <hip/hip_runtime.h>

// Shapes (fixed for this problem)
//  B=4, S=2048, D=2048, H=16, hd=128, F=3D=6144, M=B*S=8192
typedef float f32x4 __attribute__((ext_vector_type(4)));
typedef __bf16 bf16x8 __attribute__((ext_vector_type(8)));

#define EPSF 1e-6f

// ---------------- weight unit-norm (rows) + bf16 cast ----------------
// grid: 8192 blocks (6144 w_in rows + 2048 w_out rows), 256 threads
__global__ __launch_bounds__(256) void norm_w(const float* __restrict__ w_in,
                                              const float* __restrict__ w_out,
                                              __bf16* __restrict__ w_in_n,
                                              __bf16* __restrict__ w_out_n) {
  __shared__ float red[4];
  const int row = blockIdx.x;
  const float* src = (row < 6144) ? (w_in + (size_t)row * 2048)
                                  : (w_out + (size_t)(row - 6144) * 2048);
  __bf16* dst = (row < 6144) ? (w_in_n + (size_t)row * 2048)
                             : (w_out_n + (size_t)(row - 6144) * 2048);
  const int t = threadIdx.x;
  float4 v[2];
  float ss = 0.f;
#pragma unroll
  for (int i = 0; i < 2; i++) {
    v[i] = ((const float4*)src)[t + i * 256];
    ss += v[i].x * v[i].x + v[i].y * v[i].y + v[i].z * v[i].z + v[i].w * v[i].w;
  }
#pragma unroll
  for (int m = 32; m >= 1; m >>= 1) ss += __shfl_xor(ss, m);
  if ((t & 63) == 0) red[t >> 6] = ss;
  __syncthreads();
  float tot = red[0] + red[1] + red[2] + red[3];
  float sc = rsqrtf(tot + EPSF);  // unit_norm: SUM of squares
#pragma unroll
  for (int i = 0; i < 2; i++) {
    int c0 = (t + i * 256) * 4;
    dst[c0 + 0] = (__bf16)(v[i].x * sc);
    dst[c0 + 1] = (__bf16)(v[i].y * sc);
    dst[c0 + 2] = (__bf16)(v[i].z * sc);
    dst[c0 + 3] = (__bf16)(v[i].w * sc);
  }
}

// ---------------- x f32 -> bf16 ----------------
// grid: 8192 blocks x 256 thr x 8 elems = 16777216
__global__ __launch_bounds__(256) void cast_x(const float* __restrict__ x,
                                              __bf16* __restrict__ xb) {
  size_t i = ((size_t)blockIdx.x * 256 + threadIdx.x) * 8;
  float4 a = ((const float4*)(x + i))[0];
  float4 b = ((const float4*)(x + i))[1];
  bf16x8 o;
  o[0] = (__bf16)a.x; o[1] = (__bf16)a.y; o[2] = (__bf16)a.z; o[3] = (__bf16)a.w;
  o[4] = (__bf16)b.x; o[5] = (__bf16)b.y; o[6] = (__bf16)b.z; o[7] = (__bf16)b.w;
  *(bf16x8*)(xb + i) = o;
}

// ---------------- GEMM C = A[MxK] * W[NxK]^T, bf16 in, MFMA 16x16x32 ----------------
// MODE 0: C f32 row-major [MxN]
// MODE 1: scatter to qkv [3,B,H,S,hd] bf16  (col f -> t=f>>11, h=(f>>7)&15, e=f&127; row -> b=row>>11, s=row&2047)
#define BM 128
#define BN 128
#define BKK 32
#define LDK 40  // padded LDS row stride (bf16 elems), keeps 16B alignment

template <int MODE>
__global__ __launch_bounds__(256) void gemm_bt(const __bf16* __restrict__ A,
                                               const __bf16* __restrict__ W,
                                               float* __restrict__ C,
                                               __bf16* __restrict__ Cb,
                                               int M, int N, int K) {
  __shared__ __bf16 As[BM * LDK];
  __shared__ __bf16 Bs[BN * LDK];
  const int t = threadIdx.x;
  const int lane = t & 63;
  const int w = t >> 6;
  const int wm = (w >> 1) * 64;
  const int wn = (w & 1) * 64;
  const int fr = lane & 15;
  const int fk = (lane >> 4) * 8;
  const long m0 = (long)blockIdx.y * BM;
  const long n0 = (long)blockIdx.x * BN;

  f32x4 acc[4][4];
#pragma unroll
  for (int i = 0; i < 4; i++)
#pragma unroll
    for (int j = 0; j < 4; j++)
#pragma unroll
      for (int c = 0; c < 4; c++) acc[i][j][c] = 0.f;

  const int r0 = t >> 2;         // 0..63
  const int kc = (t & 3) * 8;    // 0,8,16,24

  for (int k0 = 0; k0 < K; k0 += BKK) {
#pragma unroll
    for (int i = 0; i < 2; i++) {
      int row = r0 + i * 64;
      bf16x8 av = *(const bf16x8*)(A + (m0 + row) * (long)K + k0 + kc);
      *(bf16x8*)(&As[row * LDK + kc]) = av;
      bf16x8 bv = *(const bf16x8*)(W + (n0 + row) * (long)K + k0 + kc);
      *(bf16x8*)(&Bs[row * LDK + kc]) = bv;
    }
    __syncthreads();
    bf16x8 af[4], bfr[4];
#pragma unroll
    for (int i = 0; i < 4; i++) af[i] = *(const bf16x8*)(&As[(wm + i * 16 + fr) * LDK + fk]);
#pragma unroll
    for (int j = 0; j < 4; j++) bfr[j] = *(const bf16x8*)(&Bs[(wn + j * 16 + fr) * LDK + fk]);
#pragma unroll
    for (int i = 0; i < 4; i++)
#pragma unroll
      for (int j = 0; j < 4; j++)
        acc[i][j] = __builtin_amdgcn_mfma_f32_16x16x32_bf16(af[i], bfr[j], acc[i][j], 0, 0, 0);
    __syncthreads();
  }

#pragma unroll
  for (int i = 0; i < 4; i++) {
#pragma unroll
    for (int j = 0; j < 4; j++) {
#pragma unroll
      for (int r = 0; r < 4; r++) {
        long row = m0 + wm + i * 16 + (lane >> 4) * 4 + r;  // C/D: row=(lane>>4)*4+reg
        long col = n0 + wn + j * 16 + fr;                   // C/D: col=lane&15
        float v = acc[i][j][r];
        if (MODE == 0) {
          C[row * N + col] = v;
        } else {
          long tt = col >> 11;
          long h = (col >> 7) & 15;
          long e = col & 127;
          long b = row >> 11;
          long s = row & 2047;
          Cb[(((tt * 4 + b) * 16 + h) * 2048 + s) * 128 + e] = (__bf16)v;
        }
      }
    }
  }
}

// ---------------- rms-norm q,k rows in place (one wave per 128-elem row) ----------------
// q,k are the first 2*B*H*S = 262144 rows of qkv. grid = 65536 blocks x 256.
__global__ __launch_bounds__(256) void norm_qk(__bf16* __restrict__ qkv) {
  const int w = threadIdx.x >> 6, lane = threadIdx.x & 63;
  long row = (long)blockIdx.x * 4 + w;
  __bf16* p = qkv + row * 128 + lane * 2;
  float a = (float)p[0], b = (float)p[1];
  float ss = a * a + b * b;
#pragma unroll
  for (int m = 32; m >= 1; m >>= 1) ss += __shfl_xor(ss, m);
  float sc = rsqrtf(ss * (1.f / 128.f) + EPSF);  // rms_norm: MEAN of squares
  p[0] = (__bf16)(a * sc);
  p[1] = (__bf16)(b * sc);
}

// ---------------- V transpose: [b,h,s,e] -> Vt [b,h,e,s] ----------------
// grid (2, 32, 64): x=e-tile(64), y=s-tile(64), z=bh
__global__ __launch_bounds__(256) void transpose_v(const __bf16* __restrict__ qkv,
                                                   __bf16* __restrict__ vt) {
  __shared__ __bf16 tile[64 * 65];
  const __bf16* V = qkv + 2L * 16777216 + (long)blockIdx.z * 262144;
  __bf16* Vt = vt + (long)blockIdx.z * 262144;
  const int s0 = blockIdx.y * 64, e0 = blockIdx.x * 64;
  const int t = threadIdx.x;
#pragma unroll
  for (int i = 0; i < 16; i++) {
    int idx = i * 256 + t;
    int r = idx >> 6, c = idx & 63;
    tile[r * 65 + c] = V[(long)(s0 + r) * 128 + e0 + c];
  }
  __syncthreads();
#pragma unroll
  for (int i = 0; i < 16; i++) {
    int idx = i * 256 + t;
    int r = idx >> 6, c = idx & 63;  // r = e offset, c = s offset
    Vt[(long)(e0 + r) * 2048 + s0 + c] = tile[c * 65 + r];
  }
}

// ---------------- flash attention, causal, with fused /l and rms-norm ----------------
// grid (32, 64): x = q-tile of 64, y = bh. 4 waves, each owns 16 q rows.
__global__ __launch_bounds__(256) void attn(const __bf16* __restrict__ qkv,
                                            const __bf16* __restrict__ vt,
                                            __bf16* __restrict__ an) {
  const int bh = blockIdx.y;
  const int qt = blockIdx.x;
  const int t = threadIdx.x;
  const int lane = t & 63, w = t >> 6;
  const int q0 = qt * 64 + w * 16;
  const int fr = lane & 15, fq = lane >> 4;
  const long TQ = 16777216;  // one of q/k/v in elems
  const __bf16* Q = qkv + (long)bh * 262144;
  const __bf16* Kp = qkv + TQ + (long)bh * 262144;
  const __bf16* Vp = vt + (long)bh * 262144;

  bf16x8 qf[4];
#pragma unroll
  for (int ec = 0; ec < 4; ec++)
    qf[ec] = *(const bf16x8*)(Q + (long)(q0 + fr) * 128 + ec * 32 + fq * 8);

  float m2[4], lsum[4];
#pragma unroll
  for (int r = 0; r < 4; r++) { m2[r] = -1e30f; lsum[r] = 0.f; }
  f32x4 oacc[8];
#pragma unroll
  for (int e = 0; e < 8; e++)
#pragma unroll
    for (int c = 0; c < 4; c++) oacc[e][c] = 0.f;

  __shared__ __bf16 plds[4][16 * 40];
  __bf16* pw = plds[w];

  const float sc2 = 0.08838834764831845f * 1.4426950408889634f;  // 1/sqrt(128) * log2(e)
  const int kend = q0 + 16;
  for (int k0 = 0; k0 < kend; k0 += 32) {
    f32x4 sacc[2];
#pragma unroll
    for (int ct = 0; ct < 2; ct++)
#pragma unroll
      for (int c = 0; c < 4; c++) sacc[ct][c] = 0.f;
#pragma unroll
    for (int ct = 0; ct < 2; ct++) {
#pragma unroll
      for (int ec = 0; ec < 4; ec++) {
        bf16x8 kf = *(const bf16x8*)(Kp + (long)(k0 + ct * 16 + fr) * 128 + ec * 32 + fq * 8);
        sacc[ct] = __builtin_amdgcn_mfma_f32_16x16x32_bf16(qf[ec], kf, sacc[ct], 0, 0, 0);
      }
    }
    float p0[4], p1[4], alpha[4];
#pragma unroll
    for (int r = 0; r < 4; r++) {
      int qg = q0 + fq * 4 + r;
      float v0 = ((k0 + fr) <= qg) ? sacc[0][r] * sc2 : -1e30f;
      float v1 = ((k0 + 16 + fr) <= qg) ? sacc[1][r] * sc2 : -1e30f;
      float mx = fmaxf(v0, v1);
      mx = fmaxf(mx, __shfl_xor(mx, 1));
      mx = fmaxf(mx, __shfl_xor(mx, 2));
      mx = fmaxf(mx, __shfl_xor(mx, 4));
      mx = fmaxf(mx, __shfl_xor(mx, 8));
      float mnew = fmaxf(m2[r], mx);
      alpha[r] = exp2f(m2[r] - mnew);
      m2[r] = mnew;
      p0[r] = exp2f(v0 - mnew);
      p1[r] = exp2f(v1 - mnew);
      float ps = p0[r] + p1[r];
      ps += __shfl_xor(ps, 1);
      ps += __shfl_xor(ps, 2);
      ps += __shfl_xor(ps, 4);
      ps += __shfl_xor(ps, 8);
      lsum[r] = lsum[r] * alpha[r] + ps;
    }
#pragma unroll
    for (int e = 0; e < 8; e++)
#pragma unroll
      for (int r = 0; r < 4; r++) oacc[e][r] *= alpha[r];
    // P: C-layout -> LDS -> A-layout
#pragma unroll
    for (int r = 0; r < 4; r++) {
      pw[(fq * 4 + r) * 40 + fr] = (__bf16)p0[r];
      pw[(fq * 4 + r) * 40 + 16 + fr] = (__bf16)p1[r];
    }
    bf16x8 pa = *(const bf16x8*)(&pw[fr * 40 + fq * 8]);
#pragma unroll
    for (int e = 0; e < 8; e++) {
      bf16x8 vf = *(const bf16x8*)(Vp + (long)(e * 16 + fr) * 2048 + k0 + fq * 8);
      oacc[e] = __builtin_amdgcn_mfma_f32_16x16x32_bf16(pa, vf, oacc[e], 0, 0, 0);
    }
  }
  // epilogue: /lsum, rms-norm over hd=128, write a_n [B,S,D] bf16
  const int b = bh >> 4, h = bh & 15;
#pragma unroll
  for (int r = 0; r < 4; r++) {
    float inv = 1.0f / lsum[r];
    float ssq = 0.f;
#pragma unroll
    for (int e = 0; e < 8; e++) { float v = oacc[e][r] * inv; ssq += v * v; }
    ssq += __shfl_xor(ssq, 1);
    ssq += __shfl_xor(ssq, 2);
    ssq += __shfl_xor(ssq, 4);
    ssq += __shfl_xor(ssq, 8);
    float rsc = rsqrtf(ssq * (1.f / 128.f) + EPSF) * inv;
    long s = q0 + fq * 4 + r;
    __bf16* dst = an + ((long)b * 2048 + s) * 2048 + h * 128;
#pragma unroll
    for (int e = 0; e < 8; e++) dst[e * 16 + fr] = (__bf16)(oacc[e][r] * rsc);
  }
}

// ---------------- launch ----------------
extern "C" void kernel_launch(void* const* d_in, const int* in_sizes, int n_in,
                              void* d_out, int out_size, void* d_ws, size_t ws_size,
                              hipStream_t stream) {
  const float* x = (const float*)d_in[0];
  const float* w_in = (const float*)d_in[1];
  const float* w_out = (const float*)d_in[2];
  float* out = (float*)d_out;
  char* ws = (char*)d_ws;

  // workspace layout (bytes):
  __bf16* w_in_n = (__bf16*)(ws);                      // 6144*2048*2  = 25165824
  __bf16* w_out_n = (__bf16*)(ws + 25165824);          // 2048*2048*2  =  8388608
  __bf16* xb = (__bf16*)(ws + 33554432);               // 8192*2048*2  = 33554432 (aliased by a_n)
  __bf16* an = xb;
  __bf16* qkv = (__bf16*)(ws + 67108864);              // 3*4*16*2048*128*2 = 100663296
  __bf16* vt = (__bf16*)(ws + 167772160);              // 4*16*128*2048*2   = 33554432
  // total: 201326592 bytes

  norm_w<<<8192, 256, 0, stream>>>(w_in, w_out, w_in_n, w_out_n);
  cast_x<<<8192, 256, 0, stream>>>(x, xb);
  gemm_bt<1><<<dim3(48, 64), 256, 0, stream>>>(xb, w_in_n, nullptr, qkv, 8192, 6144, 2048);
  norm_qk<<<65536, 256, 0, stream>>>(qkv);
  transpose_v<<<dim3(2, 32, 64), 256, 0, stream>>>(qkv, vt);
  attn<<<dim3(32, 64), 256, 0, stream>>>(qkv, vt, an);
  gemm_bt<0><<<dim3(16, 64), 256, 0, stream>>>(an, w_out_n, out, nullptr, 8192, 2048, 2048);
}

// Round 2
// 1023.862 us; speedup vs baseline: 1.4214x; 1.4214x over previous
//
#include <hip/hip_runtime.h>

// Shapes (fixed): B=4, S=2048, D=2048, H=16, hd=128, F=3D=6144, M=B*S=8192
typedef float f32x4 __attribute__((ext_vector_type(4)));
typedef __bf16 bf16x8 __attribute__((ext_vector_type(8)));

#define EPSF 1e-6f
#define AS1 __attribute__((address_space(1)))
#define AS3 __attribute__((address_space(3)))

__device__ static inline void gl_lds16(const __bf16* g, __bf16* l) {
  // async global->LDS, 16B/lane, LDS dest = uniform base + lane*16
  __builtin_amdgcn_global_load_lds((const AS1 void*)g, (AS3 void*)l, 16, 0, 0);
}

// ---------------- weight unit-norm (rows) + bf16 cast ----------------
__global__ __launch_bounds__(256) void norm_w(const float* __restrict__ w_in,
                                              const float* __restrict__ w_out,
                                              __bf16* __restrict__ w_in_n,
                                              __bf16* __restrict__ w_out_n) {
  __shared__ float red[4];
  const int row = blockIdx.x;
  const float* src = (row < 6144) ? (w_in + (size_t)row * 2048)
                                  : (w_out + (size_t)(row - 6144) * 2048);
  __bf16* dst = (row < 6144) ? (w_in_n + (size_t)row * 2048)
                             : (w_out_n + (size_t)(row - 6144) * 2048);
  const int t = threadIdx.x;
  float4 v[2];
  float ss = 0.f;
#pragma unroll
  for (int i = 0; i < 2; i++) {
    v[i] = ((const float4*)src)[t + i * 256];
    ss += v[i].x * v[i].x + v[i].y * v[i].y + v[i].z * v[i].z + v[i].w * v[i].w;
  }
#pragma unroll
  for (int m = 32; m >= 1; m >>= 1) ss += __shfl_xor(ss, m);
  if ((t & 63) == 0) red[t >> 6] = ss;
  __syncthreads();
  float tot = red[0] + red[1] + red[2] + red[3];
  float sc = rsqrtf(tot + EPSF);  // unit_norm: SUM of squares
#pragma unroll
  for (int i = 0; i < 2; i++) {
    int c0 = (t + i * 256) * 4;
    dst[c0 + 0] = (__bf16)(v[i].x * sc);
    dst[c0 + 1] = (__bf16)(v[i].y * sc);
    dst[c0 + 2] = (__bf16)(v[i].z * sc);
    dst[c0 + 3] = (__bf16)(v[i].w * sc);
  }
}

// ---------------- x f32 -> bf16 ----------------
__global__ __launch_bounds__(256) void cast_x(const float* __restrict__ x,
                                              __bf16* __restrict__ xb) {
  size_t i = ((size_t)blockIdx.x * 256 + threadIdx.x) * 8;
  float4 a = ((const float4*)(x + i))[0];
  float4 b = ((const float4*)(x + i))[1];
  bf16x8 o;
  o[0] = (__bf16)a.x; o[1] = (__bf16)a.y; o[2] = (__bf16)a.z; o[3] = (__bf16)a.w;
  o[4] = (__bf16)b.x; o[5] = (__bf16)b.y; o[6] = (__bf16)b.z; o[7] = (__bf16)b.w;
  *(bf16x8*)(xb + i) = o;
}

// ---------------- GEMM C = A[MxK] * W[NxK]^T, bf16, MFMA 16x16x32, m97 staging ----
// MODE 0: C f32 row-major [MxN]
// MODE 1: scatter to qkv [3,B,H,S,hd] bf16
#define BM 128
#define BN 128
#define BKK 32
// LDS stride = 32 (UNPADDED: required by global_load_lds lane->dest mapping)

template <int MODE>
__global__ __launch_bounds__(256) void gemm_bt(const __bf16* __restrict__ A,
                                               const __bf16* __restrict__ W,
                                               float* __restrict__ C,
                                               __bf16* __restrict__ Cb,
                                               int M, int N, int K) {
  __shared__ __bf16 As[BM * BKK];
  __shared__ __bf16 Bs[BN * BKK];
  const int t = threadIdx.x;
  const int lane = t & 63;
  const int w = t >> 6;
  const int wm = (w >> 1) * 64;
  const int wn = (w & 1) * 64;
  const int fr = lane & 15;
  const int fk = (lane >> 4) * 8;
  const long m0 = (long)blockIdx.y * BM;
  const long n0 = (long)blockIdx.x * BN;

  f32x4 acc[4][4];
#pragma unroll
  for (int i = 0; i < 4; i++)
#pragma unroll
    for (int j = 0; j < 4; j++)
#pragma unroll
      for (int c = 0; c < 4; c++) acc[i][j][c] = 0.f;

  // staging: wave w owns rows [w*32, w*32+32) of both tiles; 16 rows per call.
  // lane -> (row = base + lane/4, col = (lane&3)*8), LDS dest = lane*16B (matches row*64B + col*2B)
  const int srow = w * 32 + (lane >> 2);
  const int scol = (lane & 3) * 8;
  const __bf16* gA = A + (m0 + srow) * (long)K + scol;
  const __bf16* gB = W + (n0 + srow) * (long)K + scol;
  __bf16* lA0 = &As[w * 32 * BKK];
  __bf16* lA1 = &As[(w * 32 + 16) * BKK];
  __bf16* lB0 = &Bs[w * 32 * BKK];
  __bf16* lB1 = &Bs[(w * 32 + 16) * BKK];

  for (int k0 = 0; k0 < K; k0 += BKK) {
    gl_lds16(gA + k0, lA0);
    gl_lds16(gA + 16 * (long)K + k0, lA1);
    gl_lds16(gB + k0, lB0);
    gl_lds16(gB + 16 * (long)K + k0, lB1);
    __syncthreads();
    bf16x8 af[4], bfr[4];
#pragma unroll
    for (int i = 0; i < 4; i++) af[i] = *(const bf16x8*)(&As[(wm + i * 16 + fr) * BKK + fk]);
#pragma unroll
    for (int j = 0; j < 4; j++) bfr[j] = *(const bf16x8*)(&Bs[(wn + j * 16 + fr) * BKK + fk]);
#pragma unroll
    for (int i = 0; i < 4; i++)
#pragma unroll
      for (int j = 0; j < 4; j++)
        acc[i][j] = __builtin_amdgcn_mfma_f32_16x16x32_bf16(af[i], bfr[j], acc[i][j], 0, 0, 0);
    __syncthreads();
  }

#pragma unroll
  for (int i = 0; i < 4; i++) {
#pragma unroll
    for (int j = 0; j < 4; j++) {
#pragma unroll
      for (int r = 0; r < 4; r++) {
        long row = m0 + wm + i * 16 + (lane >> 4) * 4 + r;  // C/D: row=(lane>>4)*4+reg
        long col = n0 + wn + j * 16 + fr;                   // C/D: col=lane&15
        float v = acc[i][j][r];
        if (MODE == 0) {
          C[row * N + col] = v;
        } else {
          long tt = col >> 11;
          long h = (col >> 7) & 15;
          long e = col & 127;
          long b = row >> 11;
          long s = row & 2047;
          Cb[(((tt * 4 + b) * 16 + h) * 2048 + s) * 128 + e] = (__bf16)v;
        }
      }
    }
  }
}

// ---------------- rms-norm q,k rows in place ----------------
__global__ __launch_bounds__(256) void norm_qk(__bf16* __restrict__ qkv) {
  const int w = threadIdx.x >> 6, lane = threadIdx.x & 63;
  long row = (long)blockIdx.x * 4 + w;
  __bf16* p = qkv + row * 128 + lane * 2;
  float a = (float)p[0], b = (float)p[1];
  float ss = a * a + b * b;
#pragma unroll
  for (int m = 32; m >= 1; m >>= 1) ss += __shfl_xor(ss, m);
  float sc = rsqrtf(ss * (1.f / 128.f) + EPSF);  // rms_norm: MEAN of squares
  p[0] = (__bf16)(a * sc);
  p[1] = (__bf16)(b * sc);
}

// ---------------- V transpose: [b,h,s,e] -> Vt [b,h,e,s] ----------------
__global__ __launch_bounds__(256) void transpose_v(const __bf16* __restrict__ qkv,
                                                   __bf16* __restrict__ vt) {
  __shared__ __bf16 tile[64 * 65];
  const __bf16* V = qkv + 2L * 16777216 + (long)blockIdx.z * 262144;
  __bf16* Vt = vt + (long)blockIdx.z * 262144;
  const int s0 = blockIdx.y * 64, e0 = blockIdx.x * 64;
  const int t = threadIdx.x;
#pragma unroll
  for (int i = 0; i < 16; i++) {
    int idx = i * 256 + t;
    int r = idx >> 6, c = idx & 63;
    tile[r * 65 + c] = V[(long)(s0 + r) * 128 + e0 + c];
  }
  __syncthreads();
#pragma unroll
  for (int i = 0; i < 16; i++) {
    int idx = i * 256 + t;
    int r = idx >> 6, c = idx & 63;  // r = e offset, c = s offset
    Vt[(long)(e0 + r) * 2048 + s0 + c] = tile[c * 65 + r];
  }
}

// ---------------- flash attention, causal, fixed-max softmax, fused /l + rms-norm ----
// grid (16, 64): 4 waves/block; wave handles q-group g = blockIdx.x*4+w (16 rows)
// and its causal mirror 127-g, sequentially -> uniform work per wave (~64.5 k-tiles).
__global__ __launch_bounds__(256) void attn(const __bf16* __restrict__ qkv,
                                            const __bf16* __restrict__ vt,
                                            __bf16* __restrict__ an) {
  const int bh = blockIdx.y;
  const int t = threadIdx.x;
  const int lane = t & 63, w = t >> 6;
  const int g = blockIdx.x * 4 + w;  // 0..63
  const int fr = lane & 15, fq = lane >> 4;
  const __bf16* Q = qkv + (long)bh * 262144;
  const __bf16* Kp = qkv + 16777216L + (long)bh * 262144;
  const __bf16* Vp = vt + (long)bh * 262144;
  __shared__ __bf16 plds[4][16 * 40];
  __bf16* pw = plds[w];
  // scores bounded: ||q||=||k||=sqrt(128) -> |s_raw|<=128 -> |s*sc2|<=16.34 < 20
  const float sc2 = 0.08838834764831845f * 1.4426950408889634f;  // 1/sqrt(128)*log2(e)
  const float MFIX = 20.0f;
  const int b = bh >> 4, h = bh & 15;

#pragma unroll 1
  for (int qi = 0; qi < 2; qi++) {
    const int q0 = qi ? (2032 - g * 16) : g * 16;
    bf16x8 qf[4];
#pragma unroll
    for (int ec = 0; ec < 4; ec++)
      qf[ec] = *(const bf16x8*)(Q + (long)(q0 + fr) * 128 + ec * 32 + fq * 8);

    float lacc[4];
#pragma unroll
    for (int r = 0; r < 4; r++) lacc[r] = 0.f;
    f32x4 oacc[8];
#pragma unroll
    for (int e = 0; e < 8; e++)
#pragma unroll
      for (int c = 0; c < 4; c++) oacc[e][c] = 0.f;

    const int kend = q0 + 16;
    for (int k0 = 0; k0 < kend; k0 += 32) {
      f32x4 sacc[2];
#pragma unroll
      for (int ct = 0; ct < 2; ct++)
#pragma unroll
        for (int c = 0; c < 4; c++) sacc[ct][c] = 0.f;
#pragma unroll
      for (int ct = 0; ct < 2; ct++) {
#pragma unroll
        for (int ec = 0; ec < 4; ec++) {
          bf16x8 kf = *(const bf16x8*)(Kp + (long)(k0 + ct * 16 + fr) * 128 + ec * 32 + fq * 8);
          sacc[ct] = __builtin_amdgcn_mfma_f32_16x16x32_bf16(qf[ec], kf, sacc[ct], 0, 0, 0);
        }
      }
      // fixed-max softmax: p = exp2(s*sc2 - MFIX); no running max, no rescale
#pragma unroll
      for (int r = 0; r < 4; r++) {
        int qg = q0 + fq * 4 + r;
        float v0 = ((k0 + fr) <= qg) ? sacc[0][r] * sc2 - MFIX : -1e30f;
        float v1 = ((k0 + 16 + fr) <= qg) ? sacc[1][r] * sc2 - MFIX : -1e30f;
        float p0 = exp2f(v0);
        float p1 = exp2f(v1);
        lacc[r] += p0 + p1;
        pw[(fq * 4 + r) * 40 + fr] = (__bf16)p0;
        pw[(fq * 4 + r) * 40 + 16 + fr] = (__bf16)p1;
      }
      // P: C-layout -> LDS -> A-layout (wave-synchronous round-trip)
      bf16x8 pa = *(const bf16x8*)(&pw[fr * 40 + fq * 8]);
#pragma unroll
      for (int e = 0; e < 8; e++) {
        bf16x8 vf = *(const bf16x8*)(Vp + (long)(e * 16 + fr) * 2048 + k0 + fq * 8);
        oacc[e] = __builtin_amdgcn_mfma_f32_16x16x32_bf16(pa, vf, oacc[e], 0, 0, 0);
      }
    }
    // epilogue: lane-local l-sums -> cross-lane reduce once; /l + rms-norm + store
#pragma unroll
    for (int r = 0; r < 4; r++) {
      float ls = lacc[r];
      ls += __shfl_xor(ls, 1);
      ls += __shfl_xor(ls, 2);
      ls += __shfl_xor(ls, 4);
      ls += __shfl_xor(ls, 8);
      float inv = 1.0f / ls;
      float ssq = 0.f;
#pragma unroll
      for (int e = 0; e < 8; e++) { float v = oacc[e][r] * inv; ssq += v * v; }
      ssq += __shfl_xor(ssq, 1);
      ssq += __shfl_xor(ssq, 2);
      ssq += __shfl_xor(ssq, 4);
      ssq += __shfl_xor(ssq, 8);
      float rsc = rsqrtf(ssq * (1.f / 128.f) + EPSF) * inv;
      long s = q0 + fq * 4 + r;
      __bf16* dst = an + ((long)b * 2048 + s) * 2048 + h * 128;
#pragma unroll
      for (int e = 0; e < 8; e++) dst[e * 16 + fr] = (__bf16)(oacc[e][r] * rsc);
    }
  }
}

// ---------------- launch ----------------
extern "C" void kernel_launch(void* const* d_in, const int* in_sizes, int n_in,
                              void* d_out, int out_size, void* d_ws, size_t ws_size,
                              hipStream_t stream) {
  const float* x = (const float*)d_in[0];
  const float* w_in = (const float*)d_in[1];
  const float* w_out = (const float*)d_in[2];
  float* out = (float*)d_out;
  char* ws = (char*)d_ws;

  __bf16* w_in_n = (__bf16*)(ws);                      // 25165824 B
  __bf16* w_out_n = (__bf16*)(ws + 25165824);          // 8388608 B
  __bf16* xb = (__bf16*)(ws + 33554432);               // 33554432 B (aliased by a_n)
  __bf16* an = xb;
  __bf16* qkv = (__bf16*)(ws + 67108864);              // 100663296 B
  __bf16* vt = (__bf16*)(ws + 167772160);              // 33554432 B

  norm_w<<<8192, 256, 0, stream>>>(w_in, w_out, w_in_n, w_out_n);
  cast_x<<<8192, 256, 0, stream>>>(x, xb);
  gemm_bt<1><<<dim3(48, 64), 256, 0, stream>>>(xb, w_in_n, nullptr, qkv, 8192, 6144, 2048);
  norm_qk<<<65536, 256, 0, stream>>>(qkv);
  transpose_v<<<dim3(2, 32, 64), 256, 0, stream>>>(qkv, vt);
  attn<<<dim3(16, 64), 256, 0, stream>>>(qkv, vt, an);
  gemm_bt<0><<<dim3(16, 64), 256, 0, stream>>>(an, w_out_n, out, nullptr, 8192, 2048, 2048);
}

// Round 3
// 722.459 us; speedup vs baseline: 2.0144x; 1.4172x over previous
//
#include <hip/hip_runtime.h>

// Shapes (fixed): B=4, S=2048, D=2048, H=16, hd=128, F=3D=6144, M=B*S=8192
typedef float f32x4 __attribute__((ext_vector_type(4)));
typedef __bf16 bf16x8 __attribute__((ext_vector_type(8)));

#define EPSF 1e-6f
#define AS1 __attribute__((address_space(1)))
#define AS3 __attribute__((address_space(3)))

__device__ static inline void gl_lds16(const __bf16* g, __bf16* l) {
  // async global->LDS, 16B/lane, LDS dest = uniform base + lane*16
  __builtin_amdgcn_global_load_lds((const AS1 void*)g, (AS3 void*)l, 16, 0, 0);
}

// ---------------- weight unit-norm (rows) + bf16 cast ----------------
__global__ __launch_bounds__(256) void norm_w(const float* __restrict__ w_in,
                                              const float* __restrict__ w_out,
                                              __bf16* __restrict__ w_in_n,
                                              __bf16* __restrict__ w_out_n) {
  __shared__ float red[4];
  const int row = blockIdx.x;
  const float* src = (row < 6144) ? (w_in + (size_t)row * 2048)
                                  : (w_out + (size_t)(row - 6144) * 2048);
  __bf16* dst = (row < 6144) ? (w_in_n + (size_t)row * 2048)
                             : (w_out_n + (size_t)(row - 6144) * 2048);
  const int t = threadIdx.x;
  float4 v[2];
  float ss = 0.f;
#pragma unroll
  for (int i = 0; i < 2; i++) {
    v[i] = ((const float4*)src)[t + i * 256];
    ss += v[i].x * v[i].x + v[i].y * v[i].y + v[i].z * v[i].z + v[i].w * v[i].w;
  }
#pragma unroll
  for (int m = 32; m >= 1; m >>= 1) ss += __shfl_xor(ss, m);
  if ((t & 63) == 0) red[t >> 6] = ss;
  __syncthreads();
  float tot = red[0] + red[1] + red[2] + red[3];
  float sc = rsqrtf(tot + EPSF);  // unit_norm: SUM of squares
#pragma unroll
  for (int i = 0; i < 2; i++) {
    int c0 = (t + i * 256) * 4;
    dst[c0 + 0] = (__bf16)(v[i].x * sc);
    dst[c0 + 1] = (__bf16)(v[i].y * sc);
    dst[c0 + 2] = (__bf16)(v[i].z * sc);
    dst[c0 + 3] = (__bf16)(v[i].w * sc);
  }
}

// ---------------- x f32 -> bf16 ----------------
__global__ __launch_bounds__(256) void cast_x(const float* __restrict__ x,
                                              __bf16* __restrict__ xb) {
  size_t i = ((size_t)blockIdx.x * 256 + threadIdx.x) * 8;
  float4 a = ((const float4*)(x + i))[0];
  float4 b = ((const float4*)(x + i))[1];
  bf16x8 o;
  o[0] = (__bf16)a.x; o[1] = (__bf16)a.y; o[2] = (__bf16)a.z; o[3] = (__bf16)a.w;
  o[4] = (__bf16)b.x; o[5] = (__bf16)b.y; o[6] = (__bf16)b.z; o[7] = (__bf16)b.w;
  *(bf16x8*)(xb + i) = o;
}

// ---------------- GEMM C = A[MxK] * W[NxK]^T, bf16, MFMA 16x16x32, m97 staging ----
#define BM 128
#define BN 128
#define BKK 32

template <int MODE>
__global__ __launch_bounds__(256) void gemm_bt(const __bf16* __restrict__ A,
                                               const __bf16* __restrict__ W,
                                               float* __restrict__ C,
                                               __bf16* __restrict__ Cb,
                                               int M, int N, int K) {
  __shared__ __bf16 As[BM * BKK];
  __shared__ __bf16 Bs[BN * BKK];
  const int t = threadIdx.x;
  const int lane = t & 63;
  const int w = t >> 6;
  const int wm = (w >> 1) * 64;
  const int wn = (w & 1) * 64;
  const int fr = lane & 15;
  const int fk = (lane >> 4) * 8;
  const long m0 = (long)blockIdx.y * BM;
  const long n0 = (long)blockIdx.x * BN;

  f32x4 acc[4][4];
#pragma unroll
  for (int i = 0; i < 4; i++)
#pragma unroll
    for (int j = 0; j < 4; j++)
#pragma unroll
      for (int c = 0; c < 4; c++) acc[i][j][c] = 0.f;

  const int srow = w * 32 + (lane >> 2);
  const int scol = (lane & 3) * 8;
  const __bf16* gA = A + (m0 + srow) * (long)K + scol;
  const __bf16* gB = W + (n0 + srow) * (long)K + scol;
  __bf16* lA0 = &As[w * 32 * BKK];
  __bf16* lA1 = &As[(w * 32 + 16) * BKK];
  __bf16* lB0 = &Bs[w * 32 * BKK];
  __bf16* lB1 = &Bs[(w * 32 + 16) * BKK];

  for (int k0 = 0; k0 < K; k0 += BKK) {
    gl_lds16(gA + k0, lA0);
    gl_lds16(gA + 16 * (long)K + k0, lA1);
    gl_lds16(gB + k0, lB0);
    gl_lds16(gB + 16 * (long)K + k0, lB1);
    __syncthreads();
    bf16x8 af[4], bfr[4];
#pragma unroll
    for (int i = 0; i < 4; i++) af[i] = *(const bf16x8*)(&As[(wm + i * 16 + fr) * BKK + fk]);
#pragma unroll
    for (int j = 0; j < 4; j++) bfr[j] = *(const bf16x8*)(&Bs[(wn + j * 16 + fr) * BKK + fk]);
#pragma unroll
    for (int i = 0; i < 4; i++)
#pragma unroll
      for (int j = 0; j < 4; j++)
        acc[i][j] = __builtin_amdgcn_mfma_f32_16x16x32_bf16(af[i], bfr[j], acc[i][j], 0, 0, 0);
    __syncthreads();
  }

#pragma unroll
  for (int i = 0; i < 4; i++) {
#pragma unroll
    for (int j = 0; j < 4; j++) {
#pragma unroll
      for (int r = 0; r < 4; r++) {
        long row = m0 + wm + i * 16 + (lane >> 4) * 4 + r;  // C/D: row=(lane>>4)*4+reg
        long col = n0 + wn + j * 16 + fr;                   // C/D: col=lane&15
        float v = acc[i][j][r];
        if (MODE == 0) {
          C[row * N + col] = v;
        } else {
          long tt = col >> 11;
          long h = (col >> 7) & 15;
          long e = col & 127;
          long b = row >> 11;
          long s = row & 2047;
          Cb[(((tt * 4 + b) * 16 + h) * 2048 + s) * 128 + e] = (__bf16)v;
        }
      }
    }
  }
}

// ---------------- rms-norm q,k rows in place ----------------
__global__ __launch_bounds__(256) void norm_qk(__bf16* __restrict__ qkv) {
  const int w = threadIdx.x >> 6, lane = threadIdx.x & 63;
  long row = (long)blockIdx.x * 4 + w;
  __bf16* p = qkv + row * 128 + lane * 2;
  float a = (float)p[0], b = (float)p[1];
  float ss = a * a + b * b;
#pragma unroll
  for (int m = 32; m >= 1; m >>= 1) ss += __shfl_xor(ss, m);
  float sc = rsqrtf(ss * (1.f / 128.f) + EPSF);  // rms_norm: MEAN of squares
  p[0] = (__bf16)(a * sc);
  p[1] = (__bf16)(b * sc);
}

// ---------------- V transpose: [b,h,s,e] -> Vt [b,h,e,s] ----------------
__global__ __launch_bounds__(256) void transpose_v(const __bf16* __restrict__ qkv,
                                                   __bf16* __restrict__ vt) {
  __shared__ __bf16 tile[64 * 65];
  const __bf16* V = qkv + 2L * 16777216 + (long)blockIdx.z * 262144;
  __bf16* Vt = vt + (long)blockIdx.z * 262144;
  const int s0 = blockIdx.y * 64, e0 = blockIdx.x * 64;
  const int t = threadIdx.x;
#pragma unroll
  for (int i = 0; i < 16; i++) {
    int idx = i * 256 + t;
    int r = idx >> 6, c = idx & 63;
    tile[r * 65 + c] = V[(long)(s0 + r) * 128 + e0 + c];
  }
  __syncthreads();
#pragma unroll
  for (int i = 0; i < 16; i++) {
    int idx = i * 256 + t;
    int r = idx >> 6, c = idx & 63;  // r = e offset, c = s offset
    Vt[(long)(e0 + r) * 2048 + s0 + c] = tile[c * 65 + r];
  }
}

// ---------------- flash attention: LDS-shared K/V tiles, causal, fixed-max softmax ----
// grid = 1024 1-D blocks; decode L so all 16 q-tile blocks of a bh share L%8 (same XCD).
// Block: 64-row q-tile (wave owns 16 rows) + causal mirror tile; 33 uniform KT=64 stages.
// K/V staged via global_load_lds w/ XOR-swizzled source columns (bank-balanced b128 reads).
__global__ __launch_bounds__(256) void attn(const __bf16* __restrict__ qkv,
                                            const __bf16* __restrict__ vt,
                                            __bf16* __restrict__ an) {
  __shared__ __bf16 Ks[64 * 128];   // [kt row][128 elems], cols XOR-swizzled by (row&7)
  __shared__ __bf16 Vs[128 * 64];   // [e row][64 s-cols], cols XOR-swizzled by (row&7)
  __shared__ __bf16 plds[4][16 * 40];
  const int L = blockIdx.x;
  const int qt = L >> 6;                          // 0..15
  const int bh = (L & 7) + 8 * ((L >> 3) & 7);    // 0..63, same-bh blocks share L%8
  const int t = threadIdx.x;
  const int lane = t & 63, w = t >> 6;
  const int fr = lane & 15, fq = lane >> 4;
  const int swz = fr & 7;
  const __bf16* Q = qkv + (long)bh * 262144;
  const __bf16* Kbh = qkv + 16777216L + (long)bh * 262144;
  const __bf16* Vbh = vt + (long)bh * 262144;
  __bf16* pw = plds[w];
  const float sc2 = 0.08838834764831845f * 1.4426950408889634f;  // 1/sqrt(128)*log2(e)
  const float MFIX = 20.0f;  // scores bounded by 16.34 after rms-norm; softmax shift-invariant
  const int b = bh >> 4, h = bh & 15;

  // staging source addresses (per-lane, swizzled); K: slot s=j*256+t -> row j*16+(t>>4), blk (t&15)^((t>>4)&7)
  const __bf16* gK = Kbh + (long)(t >> 4) * 128 + ((t & 15) ^ ((t >> 4) & 7)) * 8;
  // V: slot s=j*256+t -> row j*32+(t>>3), blk (t&7)^((t>>3)&7)
  const __bf16* gV = Vbh + (long)(t >> 3) * 2048 + ((t & 7) ^ ((t >> 3) & 7)) * 8;
  __bf16* lK = &Ks[w * 512];  // + j*2048 per call (slot base (j*256+w*64)*8)
  __bf16* lV = &Vs[w * 512];

#pragma unroll 1
  for (int side = 0; side < 2; side++) {
    const int qi = side ? (31 - qt) : qt;  // q-tile index 0..31
    const int q0 = qi * 64 + w * 16;
    bf16x8 qf[4];
#pragma unroll
    for (int ec = 0; ec < 4; ec++)
      qf[ec] = *(const bf16x8*)(Q + (long)(q0 + fr) * 128 + ec * 32 + fq * 8);

    float lacc[4];
#pragma unroll
    for (int r = 0; r < 4; r++) lacc[r] = 0.f;
    f32x4 oacc[8];
#pragma unroll
    for (int e = 0; e < 8; e++)
#pragma unroll
      for (int c = 0; c < 4; c++) oacc[e][c] = 0.f;

    const int nst = qi + 1;
#pragma unroll 1
    for (int st = 0; st < nst; st++) {
      const int k0 = st * 64;
#pragma unroll
      for (int j = 0; j < 4; j++)
        gl_lds16(gK + (long)(k0 + j * 16) * 128, lK + j * 2048);
#pragma unroll
      for (int j = 0; j < 4; j++)
        gl_lds16(gV + (long)j * 65536 + k0, lV + j * 2048);
      __syncthreads();
#pragma unroll
      for (int half = 0; half < 2; half++) {
        const int k32 = k0 + half * 32;
        f32x4 sacc[2];
#pragma unroll
        for (int ct = 0; ct < 2; ct++)
#pragma unroll
          for (int c = 0; c < 4; c++) sacc[ct][c] = 0.f;
#pragma unroll
        for (int ct = 0; ct < 2; ct++) {
#pragma unroll
          for (int ec = 0; ec < 4; ec++) {
            bf16x8 kf = *(const bf16x8*)(&Ks[(half * 32 + ct * 16 + fr) * 128 +
                                             ((ec * 4 + fq) ^ swz) * 8]);
            sacc[ct] = __builtin_amdgcn_mfma_f32_16x16x32_bf16(qf[ec], kf, sacc[ct], 0, 0, 0);
          }
        }
#pragma unroll
        for (int r = 0; r < 4; r++) {
          int qg = q0 + fq * 4 + r;
          float v0 = ((k32 + fr) <= qg) ? sacc[0][r] * sc2 - MFIX : -1e30f;
          float v1 = ((k32 + 16 + fr) <= qg) ? sacc[1][r] * sc2 - MFIX : -1e30f;
          float p0 = exp2f(v0);
          float p1 = exp2f(v1);
          lacc[r] += p0 + p1;
          pw[(fq * 4 + r) * 40 + fr] = (__bf16)p0;
          pw[(fq * 4 + r) * 40 + 16 + fr] = (__bf16)p1;
        }
        bf16x8 pa = *(const bf16x8*)(&pw[fr * 40 + fq * 8]);
#pragma unroll
        for (int e = 0; e < 8; e++) {
          bf16x8 vf = *(const bf16x8*)(&Vs[(e * 16 + fr) * 64 +
                                           ((half * 4 + fq) ^ swz) * 8]);
          oacc[e] = __builtin_amdgcn_mfma_f32_16x16x32_bf16(pa, vf, oacc[e], 0, 0, 0);
        }
      }
      __syncthreads();
    }
    // epilogue: reduce lane-local l; /l + rms-norm + store
#pragma unroll
    for (int r = 0; r < 4; r++) {
      float ls = lacc[r];
      ls += __shfl_xor(ls, 1);
      ls += __shfl_xor(ls, 2);
      ls += __shfl_xor(ls, 4);
      ls += __shfl_xor(ls, 8);
      float inv = 1.0f / ls;
      float ssq = 0.f;
#pragma unroll
      for (int e = 0; e < 8; e++) { float v = oacc[e][r] * inv; ssq += v * v; }
      ssq += __shfl_xor(ssq, 1);
      ssq += __shfl_xor(ssq, 2);
      ssq += __shfl_xor(ssq, 4);
      ssq += __shfl_xor(ssq, 8);
      float rsc = rsqrtf(ssq * (1.f / 128.f) + EPSF) * inv;
      long s = q0 + fq * 4 + r;
      __bf16* dst = an + ((long)b * 2048 + s) * 2048 + h * 128;
#pragma unroll
      for (int e = 0; e < 8; e++) dst[e * 16 + fr] = (__bf16)(oacc[e][r] * rsc);
    }
  }
}

// ---------------- launch ----------------
extern "C" void kernel_launch(void* const* d_in, const int* in_sizes, int n_in,
                              void* d_out, int out_size, void* d_ws, size_t ws_size,
                              hipStream_t stream) {
  const float* x = (const float*)d_in[0];
  const float* w_in = (const float*)d_in[1];
  const float* w_out = (const float*)d_in[2];
  float* out = (float*)d_out;
  char* ws = (char*)d_ws;

  __bf16* w_in_n = (__bf16*)(ws);                      // 25165824 B
  __bf16* w_out_n = (__bf16*)(ws + 25165824);          // 8388608 B
  __bf16* xb = (__bf16*)(ws + 33554432);               // 33554432 B (aliased by a_n)
  __bf16* an = xb;
  __bf16* qkv = (__bf16*)(ws + 67108864);              // 100663296 B
  __bf16* vt = (__bf16*)(ws + 167772160);              // 33554432 B

  norm_w<<<8192, 256, 0, stream>>>(w_in, w_out, w_in_n, w_out_n);
  cast_x<<<8192, 256, 0, stream>>>(x, xb);
  gemm_bt<1><<<dim3(48, 64), 256, 0, stream>>>(xb, w_in_n, nullptr, qkv, 8192, 6144, 2048);
  norm_qk<<<65536, 256, 0, stream>>>(qkv);
  transpose_v<<<dim3(2, 32, 64), 256, 0, stream>>>(qkv, vt);
  attn<<<1024, 256, 0, stream>>>(qkv, vt, an);
  gemm_bt<0><<<dim3(16, 64), 256, 0, stream>>>(an, w_out_n, out, nullptr, 8192, 2048, 2048);
}

// Round 4
// 688.302 us; speedup vs baseline: 2.1144x; 1.0496x over previous
//
#include <hip/hip_runtime.h>

// Shapes (fixed): B=4, S=2048, D=2048, H=16, hd=128, F=3D=6144, M=B*S=8192
typedef float f32x4 __attribute__((ext_vector_type(4)));
typedef __bf16 bf16x8 __attribute__((ext_vector_type(8)));

#define EPSF 1e-6f
#define AS1 __attribute__((address_space(1)))
#define AS3 __attribute__((address_space(3)))

__device__ static inline void gl_lds16(const __bf16* g, __bf16* l) {
  // async global->LDS, 16B/lane, LDS dest = uniform base + lane*16
  __builtin_amdgcn_global_load_lds((const AS1 void*)g, (AS3 void*)l, 16, 0, 0);
}

// ---------------- weight unit-norm (rows) + bf16 cast ----------------
__global__ __launch_bounds__(256) void norm_w(const float* __restrict__ w_in,
                                              const float* __restrict__ w_out,
                                              __bf16* __restrict__ w_in_n,
                                              __bf16* __restrict__ w_out_n) {
  __shared__ float red[4];
  const int row = blockIdx.x;
  const float* src = (row < 6144) ? (w_in + (size_t)row * 2048)
                                  : (w_out + (size_t)(row - 6144) * 2048);
  __bf16* dst = (row < 6144) ? (w_in_n + (size_t)row * 2048)
                             : (w_out_n + (size_t)(row - 6144) * 2048);
  const int t = threadIdx.x;
  float4 v[2];
  float ss = 0.f;
#pragma unroll
  for (int i = 0; i < 2; i++) {
    v[i] = ((const float4*)src)[t + i * 256];
    ss += v[i].x * v[i].x + v[i].y * v[i].y + v[i].z * v[i].z + v[i].w * v[i].w;
  }
#pragma unroll
  for (int m = 32; m >= 1; m >>= 1) ss += __shfl_xor(ss, m);
  if ((t & 63) == 0) red[t >> 6] = ss;
  __syncthreads();
  float tot = red[0] + red[1] + red[2] + red[3];
  float sc = rsqrtf(tot + EPSF);  // unit_norm: SUM of squares
#pragma unroll
  for (int i = 0; i < 2; i++) {
    int c0 = (t + i * 256) * 4;
    dst[c0 + 0] = (__bf16)(v[i].x * sc);
    dst[c0 + 1] = (__bf16)(v[i].y * sc);
    dst[c0 + 2] = (__bf16)(v[i].z * sc);
    dst[c0 + 3] = (__bf16)(v[i].w * sc);
  }
}

// ---------------- x f32 -> bf16 ----------------
__global__ __launch_bounds__(256) void cast_x(const float* __restrict__ x,
                                              __bf16* __restrict__ xb) {
  size_t i = ((size_t)blockIdx.x * 256 + threadIdx.x) * 8;
  float4 a = ((const float4*)(x + i))[0];
  float4 b = ((const float4*)(x + i))[1];
  bf16x8 o;
  o[0] = (__bf16)a.x; o[1] = (__bf16)a.y; o[2] = (__bf16)a.z; o[3] = (__bf16)a.w;
  o[4] = (__bf16)b.x; o[5] = (__bf16)b.y; o[6] = (__bf16)b.z; o[7] = (__bf16)b.w;
  *(bf16x8*)(xb + i) = o;
}

// ---------------- GEMM C = A[MxK] * W[NxK]^T, bf16, MFMA 16x16x32, m97 staging ----
// MODE 0: C f32 row-major [MxN]
// MODE 1: fused epilogue. Each n-block covers exactly one (t,h) head (BN=128 = hd).
//         t<2 (q,k): block-local rms-norm over e (LDS cross-wave exchange), scatter
//         normalized bf16 to qkv [t,b,h,s,e]. t==2 (v): scatter transposed to vt [b,h,e,s].
#define BM 128
#define BN 128
#define BKK 32

template <int MODE>
__global__ __launch_bounds__(256) void gemm_bt(const __bf16* __restrict__ A,
                                               const __bf16* __restrict__ W,
                                               float* __restrict__ C,
                                               __bf16* __restrict__ Cb,
                                               __bf16* __restrict__ Vtb,
                                               int M, int N, int K) {
  __shared__ __bf16 As[BM * BKK];
  __shared__ __bf16 Bs[BN * BKK];
  const int t = threadIdx.x;
  const int lane = t & 63;
  const int w = t >> 6;
  const int wm = (w >> 1) * 64;
  const int wn = (w & 1) * 64;
  const int fr = lane & 15;
  const int fk = (lane >> 4) * 8;
  const int fq = lane >> 4;
  const long m0 = (long)blockIdx.y * BM;
  const long n0 = (long)blockIdx.x * BN;

  f32x4 acc[4][4];
#pragma unroll
  for (int i = 0; i < 4; i++)
#pragma unroll
    for (int j = 0; j < 4; j++)
#pragma unroll
      for (int c = 0; c < 4; c++) acc[i][j][c] = 0.f;

  const int srow = w * 32 + (lane >> 2);
  const int scol = (lane & 3) * 8;
  const __bf16* gA = A + (m0 + srow) * (long)K + scol;
  const __bf16* gB = W + (n0 + srow) * (long)K + scol;
  __bf16* lA0 = &As[w * 32 * BKK];
  __bf16* lA1 = &As[(w * 32 + 16) * BKK];
  __bf16* lB0 = &Bs[w * 32 * BKK];
  __bf16* lB1 = &Bs[(w * 32 + 16) * BKK];

  for (int k0 = 0; k0 < K; k0 += BKK) {
    gl_lds16(gA + k0, lA0);
    gl_lds16(gA + 16 * (long)K + k0, lA1);
    gl_lds16(gB + k0, lB0);
    gl_lds16(gB + 16 * (long)K + k0, lB1);
    __syncthreads();
    bf16x8 af[4], bfr[4];
#pragma unroll
    for (int i = 0; i < 4; i++) af[i] = *(const bf16x8*)(&As[(wm + i * 16 + fr) * BKK + fk]);
#pragma unroll
    for (int j = 0; j < 4; j++) bfr[j] = *(const bf16x8*)(&Bs[(wn + j * 16 + fr) * BKK + fk]);
#pragma unroll
    for (int i = 0; i < 4; i++)
#pragma unroll
      for (int j = 0; j < 4; j++)
        acc[i][j] = __builtin_amdgcn_mfma_f32_16x16x32_bf16(af[i], bfr[j], acc[i][j], 0, 0, 0);
    __syncthreads();
  }

  if (MODE == 0) {
#pragma unroll
    for (int i = 0; i < 4; i++)
#pragma unroll
      for (int j = 0; j < 4; j++)
#pragma unroll
        for (int r = 0; r < 4; r++) {
          long row = m0 + wm + i * 16 + fq * 4 + r;  // C/D: row=(lane>>4)*4+reg
          long col = n0 + wn + j * 16 + fr;          // C/D: col=lane&15
          C[row * N + col] = acc[i][j][r];
        }
  } else {
    const int tt = (int)(n0 >> 11);        // 0=q,1=k,2=v (block-uniform)
    const int hh = (int)((n0 >> 7) & 15);  // head (block-uniform)
    if (tt < 2) {
      // fused rms-norm over e (128 = this block's col range)
      __shared__ float rss[4][64];
#pragma unroll
      for (int i = 0; i < 4; i++)
#pragma unroll
        for (int r = 0; r < 4; r++) {
          float s2 = 0.f;
#pragma unroll
          for (int j = 0; j < 4; j++) s2 += acc[i][j][r] * acc[i][j][r];
          s2 += __shfl_xor(s2, 1);
          s2 += __shfl_xor(s2, 2);
          s2 += __shfl_xor(s2, 4);
          s2 += __shfl_xor(s2, 8);
          if (fr == 0) rss[w][i * 16 + fq * 4 + r] = s2;
        }
      __syncthreads();
#pragma unroll
      for (int i = 0; i < 4; i++)
#pragma unroll
        for (int r = 0; r < 4; r++) {
          int rl = i * 16 + fq * 4 + r;
          float tot = rss[w][rl] + rss[w ^ 1][rl];
          float sc = rsqrtf(tot * (1.f / 128.f) + EPSF);
          long row = m0 + wm + rl;
          long bb = row >> 11, ss = row & 2047;
          __bf16* base = Cb + ((((long)tt * 4 + bb) * 16 + hh) * 2048 + ss) * 128;
#pragma unroll
          for (int j = 0; j < 4; j++)
            base[wn + j * 16 + fr] = (__bf16)(acc[i][j][r] * sc);
        }
    } else {
      // V: scatter transposed into vt [b,h,e,s]
#pragma unroll
      for (int i = 0; i < 4; i++)
#pragma unroll
        for (int r = 0; r < 4; r++) {
          long row = m0 + wm + i * 16 + fq * 4 + r;
          long bb = row >> 11, ss = row & 2047;
          __bf16* base = Vtb + ((bb * 16 + hh) * 128) * 2048 + ss;
#pragma unroll
          for (int j = 0; j < 4; j++)
            base[(long)(wn + j * 16 + fr) * 2048] = (__bf16)(acc[i][j][r]);
        }
    }
  }
}

// ---------------- flash attention v3: 128-row q-macro-tile + mirror, LDS K/V ----
// grid = 512 blocks; qt = L>>6 (0..7), bh decoded so same-XCD blocks share bh&7.
// Wave owns two 16-row fragments: q0a = qi*128 + w*16, q0b = q0a + 64 (interleaved
// so causal trip counts are wave-uniform). Exactly one masked diagonal 32-chunk per
// fragment; earlier chunks run compare-free exp2(fma) fast path; later chunks skipped.
__global__ __launch_bounds__(256) void attn(const __bf16* __restrict__ qkv,
                                            const __bf16* __restrict__ vt,
                                            __bf16* __restrict__ an) {
  __shared__ __bf16 Ks[64 * 128];   // [k row][128 e], 16B-blocks XOR-swizzled by (row&7)
  __shared__ __bf16 Vs[128 * 64];   // [e row][64 s], 16B-blocks XOR-swizzled by (row&7)
  __shared__ __bf16 plds[4][2][16 * 40];
  const int L = blockIdx.x;
  const int qt = L >> 6;                        // 0..7
  const int bh = (L & 7) + 8 * ((L >> 3) & 7);  // 0..63
  const int t = threadIdx.x;
  const int lane = t & 63, w = t >> 6;
  const int fr = lane & 15, fq = lane >> 4;
  const int swz = fr & 7;
  const __bf16* Q = qkv + (long)bh * 262144;
  const __bf16* Kbh = qkv + 16777216L + (long)bh * 262144;
  const __bf16* Vbh = vt + (long)bh * 262144;
  __bf16* pw0 = plds[w][0];
  __bf16* pw1 = plds[w][1];
  const float sc2 = 0.08838834764831845f * 1.4426950408889634f;  // 1/sqrt(128)*log2(e)
  const float MFIX = 20.0f;  // |score*log2e/sqrt(hd)| <= 16.34 after rms-norm
  const int b = bh >> 4, h = bh & 15;

  const __bf16* gK = Kbh + (long)(t >> 4) * 128 + ((t & 15) ^ ((t >> 4) & 7)) * 8;
  const __bf16* gV = Vbh + (long)(t >> 3) * 2048 + ((t & 7) ^ ((t >> 3) & 7)) * 8;
  __bf16* lK = &Ks[w * 512];
  __bf16* lV = &Vs[w * 512];

#pragma unroll 1
  for (int side = 0; side < 2; side++) {
    const int qi = side ? (15 - qt) : qt;  // macro-tile index 0..15
    const int q0a = qi * 128 + w * 16;
    const int q0b = q0a + 64;
    const int cha = q0a >> 5, chb = q0b >> 5;  // diagonal chunk per fragment
    bf16x8 qfa[4], qfb[4];
#pragma unroll
    for (int ec = 0; ec < 4; ec++) {
      qfa[ec] = *(const bf16x8*)(Q + (long)(q0a + fr) * 128 + ec * 32 + fq * 8);
      qfb[ec] = *(const bf16x8*)(Q + (long)(q0b + fr) * 128 + ec * 32 + fq * 8);
    }
    float lacca[4], laccb[4];
#pragma unroll
    for (int r = 0; r < 4; r++) { lacca[r] = 0.f; laccb[r] = 0.f; }
    f32x4 oacca[8], oaccb[8];
#pragma unroll
    for (int e = 0; e < 8; e++)
#pragma unroll
      for (int c = 0; c < 4; c++) { oacca[e][c] = 0.f; oaccb[e][c] = 0.f; }

    const int nst = 2 * qi + 2;
#pragma unroll 1
    for (int st = 0; st < nst; st++) {
      const int k0 = st * 64;
#pragma unroll
      for (int j = 0; j < 4; j++)
        gl_lds16(gK + (long)(k0 + j * 16) * 128, lK + j * 2048);
#pragma unroll
      for (int j = 0; j < 4; j++)
        gl_lds16(gV + (long)j * 65536 + k0, lV + j * 2048);
      __syncthreads();
#pragma unroll
      for (int half = 0; half < 2; half++) {
        const int k32 = k0 + half * 32;
        const int ch = k32 >> 5;
        const bool da = (ch <= cha), db = (ch <= chb);  // wave-uniform
        f32x4 sa[2], sb[2];
#pragma unroll
        for (int ct = 0; ct < 2; ct++)
#pragma unroll
          for (int c = 0; c < 4; c++) { sa[ct][c] = 0.f; sb[ct][c] = 0.f; }
#pragma unroll
        for (int ct = 0; ct < 2; ct++) {
#pragma unroll
          for (int ec = 0; ec < 4; ec++) {
            bf16x8 kf = *(const bf16x8*)(&Ks[(half * 32 + ct * 16 + fr) * 128 +
                                             ((ec * 4 + fq) ^ swz) * 8]);
            if (da) sa[ct] = __builtin_amdgcn_mfma_f32_16x16x32_bf16(qfa[ec], kf, sa[ct], 0, 0, 0);
            if (db) sb[ct] = __builtin_amdgcn_mfma_f32_16x16x32_bf16(qfb[ec], kf, sb[ct], 0, 0, 0);
          }
        }
        if (da) {
          if (ch == cha) {  // diagonal: masked
#pragma unroll
            for (int r = 0; r < 4; r++) {
              int qg = q0a + fq * 4 + r;
              float p0 = exp2f(((k32 + fr) <= qg) ? sa[0][r] * sc2 - MFIX : -1e30f);
              float p1 = exp2f(((k32 + 16 + fr) <= qg) ? sa[1][r] * sc2 - MFIX : -1e30f);
              lacca[r] += p0 + p1;
              pw0[(fq * 4 + r) * 40 + fr] = (__bf16)p0;
              pw0[(fq * 4 + r) * 40 + 16 + fr] = (__bf16)p1;
            }
          } else {  // fast path, no compares
#pragma unroll
            for (int r = 0; r < 4; r++) {
              float p0 = exp2f(__builtin_fmaf(sa[0][r], sc2, -MFIX));
              float p1 = exp2f(__builtin_fmaf(sa[1][r], sc2, -MFIX));
              lacca[r] += p0 + p1;
              pw0[(fq * 4 + r) * 40 + fr] = (__bf16)p0;
              pw0[(fq * 4 + r) * 40 + 16 + fr] = (__bf16)p1;
            }
          }
        }
        if (db) {
          if (ch == chb) {
#pragma unroll
            for (int r = 0; r < 4; r++) {
              int qg = q0b + fq * 4 + r;
              float p0 = exp2f(((k32 + fr) <= qg) ? sb[0][r] * sc2 - MFIX : -1e30f);
              float p1 = exp2f(((k32 + 16 + fr) <= qg) ? sb[1][r] * sc2 - MFIX : -1e30f);
              laccb[r] += p0 + p1;
              pw1[(fq * 4 + r) * 40 + fr] = (__bf16)p0;
              pw1[(fq * 4 + r) * 40 + 16 + fr] = (__bf16)p1;
            }
          } else {
#pragma unroll
            for (int r = 0; r < 4; r++) {
              float p0 = exp2f(__builtin_fmaf(sb[0][r], sc2, -MFIX));
              float p1 = exp2f(__builtin_fmaf(sb[1][r], sc2, -MFIX));
              laccb[r] += p0 + p1;
              pw1[(fq * 4 + r) * 40 + fr] = (__bf16)p0;
              pw1[(fq * 4 + r) * 40 + 16 + fr] = (__bf16)p1;
            }
          }
        }
        bf16x8 pa0, pa1;
        if (da) pa0 = *(const bf16x8*)(&pw0[fr * 40 + fq * 8]);
        if (db) pa1 = *(const bf16x8*)(&pw1[fr * 40 + fq * 8]);
#pragma unroll
        for (int e = 0; e < 8; e++) {
          bf16x8 vf = *(const bf16x8*)(&Vs[(e * 16 + fr) * 64 +
                                           ((half * 4 + fq) ^ swz) * 8]);
          if (da) oacca[e] = __builtin_amdgcn_mfma_f32_16x16x32_bf16(pa0, vf, oacca[e], 0, 0, 0);
          if (db) oaccb[e] = __builtin_amdgcn_mfma_f32_16x16x32_bf16(pa1, vf, oaccb[e], 0, 0, 0);
        }
      }
      __syncthreads();
    }
    // epilogue per fragment: reduce l; /l + rms-norm + store
#pragma unroll
    for (int frag = 0; frag < 2; frag++) {
      const int q0 = frag ? q0b : q0a;
      float* lacc = frag ? laccb : lacca;
      f32x4* oacc = frag ? oaccb : oacca;
#pragma unroll
      for (int r = 0; r < 4; r++) {
        float ls = lacc[r];
        ls += __shfl_xor(ls, 1);
        ls += __shfl_xor(ls, 2);
        ls += __shfl_xor(ls, 4);
        ls += __shfl_xor(ls, 8);
        float inv = 1.0f / ls;
        float ssq = 0.f;
#pragma unroll
        for (int e = 0; e < 8; e++) { float v = oacc[e][r] * inv; ssq += v * v; }
        ssq += __shfl_xor(ssq, 1);
        ssq += __shfl_xor(ssq, 2);
        ssq += __shfl_xor(ssq, 4);
        ssq += __shfl_xor(ssq, 8);
        float rsc = rsqrtf(ssq * (1.f / 128.f) + EPSF) * inv;
        long s = q0 + fq * 4 + r;
        __bf16* dst = an + ((long)b * 2048 + s) * 2048 + h * 128;
#pragma unroll
        for (int e = 0; e < 8; e++) dst[e * 16 + fr] = (__bf16)(oacc[e][r] * rsc);
      }
    }
  }
}

// ---------------- launch ----------------
extern "C" void kernel_launch(void* const* d_in, const int* in_sizes, int n_in,
                              void* d_out, int out_size, void* d_ws, size_t ws_size,
                              hipStream_t stream) {
  const float* x = (const float*)d_in[0];
  const float* w_in = (const float*)d_in[1];
  const float* w_out = (const float*)d_in[2];
  float* out = (float*)d_out;
  char* ws = (char*)d_ws;

  __bf16* w_in_n = (__bf16*)(ws);                      // 25165824 B
  __bf16* w_out_n = (__bf16*)(ws + 25165824);          // 8388608 B
  __bf16* xb = (__bf16*)(ws + 33554432);               // 33554432 B (aliased by a_n)
  __bf16* an = xb;
  __bf16* qkv = (__bf16*)(ws + 67108864);              // q,k used (v region unused)
  __bf16* vt = (__bf16*)(ws + 167772160);              // 33554432 B

  norm_w<<<8192, 256, 0, stream>>>(w_in, w_out, w_in_n, w_out_n);
  cast_x<<<8192, 256, 0, stream>>>(x, xb);
  gemm_bt<1><<<dim3(48, 64), 256, 0, stream>>>(xb, w_in_n, nullptr, qkv, vt, 8192, 6144, 2048);
  attn<<<512, 256, 0, stream>>>(qkv, vt, an);
  gemm_bt<0><<<dim3(16, 64), 256, 0, stream>>>(an, w_out_n, out, nullptr, nullptr, 8192, 2048, 2048);
}

// Round 5
// 643.895 us; speedup vs baseline: 2.2602x; 1.0690x over previous
//
#include <hip/hip_runtime.h>

// Shapes (fixed): B=4, S=2048, D=2048, H=16, hd=128, F=3D=6144, M=B*S=8192
typedef float f32x4 __attribute__((ext_vector_type(4)));
typedef __bf16 bf16x8 __attribute__((ext_vector_type(8)));

#define EPSF 1e-6f
#define AS1 __attribute__((address_space(1)))
#define AS3 __attribute__((address_space(3)))

__device__ static inline void gl_lds16(const __bf16* g, __bf16* l) {
  // async global->LDS, 16B/lane, LDS dest = uniform base + lane*16
  __builtin_amdgcn_global_load_lds((const AS1 void*)g, (AS3 void*)l, 16, 0, 0);
}

// ---------------- weight unit-norm (rows) + bf16 cast ----------------
__global__ __launch_bounds__(256) void norm_w(const float* __restrict__ w_in,
                                              const float* __restrict__ w_out,
                                              __bf16* __restrict__ w_in_n,
                                              __bf16* __restrict__ w_out_n) {
  __shared__ float red[4];
  const int row = blockIdx.x;
  const float* src = (row < 6144) ? (w_in + (size_t)row * 2048)
                                  : (w_out + (size_t)(row - 6144) * 2048);
  __bf16* dst = (row < 6144) ? (w_in_n + (size_t)row * 2048)
                             : (w_out_n + (size_t)(row - 6144) * 2048);
  const int t = threadIdx.x;
  float4 v[2];
  float ss = 0.f;
#pragma unroll
  for (int i = 0; i < 2; i++) {
    v[i] = ((const float4*)src)[t + i * 256];
    ss += v[i].x * v[i].x + v[i].y * v[i].y + v[i].z * v[i].z + v[i].w * v[i].w;
  }
#pragma unroll
  for (int m = 32; m >= 1; m >>= 1) ss += __shfl_xor(ss, m);
  if ((t & 63) == 0) red[t >> 6] = ss;
  __syncthreads();
  float tot = red[0] + red[1] + red[2] + red[3];
  float sc = rsqrtf(tot + EPSF);  // unit_norm: SUM of squares
#pragma unroll
  for (int i = 0; i < 2; i++) {
    int c0 = (t + i * 256) * 4;
    dst[c0 + 0] = (__bf16)(v[i].x * sc);
    dst[c0 + 1] = (__bf16)(v[i].y * sc);
    dst[c0 + 2] = (__bf16)(v[i].z * sc);
    dst[c0 + 3] = (__bf16)(v[i].w * sc);
  }
}

// ---------------- x f32 -> bf16 ----------------
__global__ __launch_bounds__(256) void cast_x(const float* __restrict__ x,
                                              __bf16* __restrict__ xb) {
  size_t i = ((size_t)blockIdx.x * 256 + threadIdx.x) * 8;
  float4 a = ((const float4*)(x + i))[0];
  float4 b = ((const float4*)(x + i))[1];
  bf16x8 o;
  o[0] = (__bf16)a.x; o[1] = (__bf16)a.y; o[2] = (__bf16)a.z; o[3] = (__bf16)a.w;
  o[4] = (__bf16)b.x; o[5] = (__bf16)b.y; o[6] = (__bf16)b.z; o[7] = (__bf16)b.w;
  *(bf16x8*)(xb + i) = o;
}

// ---------------- GEMM C = A[MxK] * W[NxK]^T, bf16, MFMA 16x16x32, m97 staging ----
// MODE 0: C f32 row-major [MxN]
// MODE 1: fused epilogue. Each n-block covers exactly one (t,h) head (BN=128 = hd).
//         t<2 (q,k): block-local rms-norm over e, scatter bf16 to qkv [t,b,h,s,e].
//         t==2 (v): scatter transposed to vt [b,h,e,s].
#define BM 128
#define BN 128
#define BKK 32

template <int MODE>
__global__ __launch_bounds__(256) void gemm_bt(const __bf16* __restrict__ A,
                                               const __bf16* __restrict__ W,
                                               float* __restrict__ C,
                                               __bf16* __restrict__ Cb,
                                               __bf16* __restrict__ Vtb,
                                               int M, int N, int K) {
  __shared__ __bf16 As[BM * BKK];
  __shared__ __bf16 Bs[BN * BKK];
  const int t = threadIdx.x;
  const int lane = t & 63;
  const int w = t >> 6;
  const int wm = (w >> 1) * 64;
  const int wn = (w & 1) * 64;
  const int fr = lane & 15;
  const int fk = (lane >> 4) * 8;
  const int fq = lane >> 4;
  const long m0 = (long)blockIdx.y * BM;
  const long n0 = (long)blockIdx.x * BN;

  f32x4 acc[4][4];
#pragma unroll
  for (int i = 0; i < 4; i++)
#pragma unroll
    for (int j = 0; j < 4; j++)
#pragma unroll
      for (int c = 0; c < 4; c++) acc[i][j][c] = 0.f;

  const int srow = w * 32 + (lane >> 2);
  const int scol = (lane & 3) * 8;
  const __bf16* gA = A + (m0 + srow) * (long)K + scol;
  const __bf16* gB = W + (n0 + srow) * (long)K + scol;
  __bf16* lA0 = &As[w * 32 * BKK];
  __bf16* lA1 = &As[(w * 32 + 16) * BKK];
  __bf16* lB0 = &Bs[w * 32 * BKK];
  __bf16* lB1 = &Bs[(w * 32 + 16) * BKK];

  for (int k0 = 0; k0 < K; k0 += BKK) {
    gl_lds16(gA + k0, lA0);
    gl_lds16(gA + 16 * (long)K + k0, lA1);
    gl_lds16(gB + k0, lB0);
    gl_lds16(gB + 16 * (long)K + k0, lB1);
    __syncthreads();
    bf16x8 af[4], bfr[4];
#pragma unroll
    for (int i = 0; i < 4; i++) af[i] = *(const bf16x8*)(&As[(wm + i * 16 + fr) * BKK + fk]);
#pragma unroll
    for (int j = 0; j < 4; j++) bfr[j] = *(const bf16x8*)(&Bs[(wn + j * 16 + fr) * BKK + fk]);
#pragma unroll
    for (int i = 0; i < 4; i++)
#pragma unroll
      for (int j = 0; j < 4; j++)
        acc[i][j] = __builtin_amdgcn_mfma_f32_16x16x32_bf16(af[i], bfr[j], acc[i][j], 0, 0, 0);
    __syncthreads();
  }

  if (MODE == 0) {
#pragma unroll
    for (int i = 0; i < 4; i++)
#pragma unroll
      for (int j = 0; j < 4; j++)
#pragma unroll
        for (int r = 0; r < 4; r++) {
          long row = m0 + wm + i * 16 + fq * 4 + r;  // C/D: row=(lane>>4)*4+reg
          long col = n0 + wn + j * 16 + fr;          // C/D: col=lane&15
          C[row * N + col] = acc[i][j][r];
        }
  } else {
    const int tt = (int)(n0 >> 11);        // 0=q,1=k,2=v (block-uniform)
    const int hh = (int)((n0 >> 7) & 15);  // head (block-uniform)
    if (tt < 2) {
      __shared__ float rss[4][64];
#pragma unroll
      for (int i = 0; i < 4; i++)
#pragma unroll
        for (int r = 0; r < 4; r++) {
          float s2 = 0.f;
#pragma unroll
          for (int j = 0; j < 4; j++) s2 += acc[i][j][r] * acc[i][j][r];
          s2 += __shfl_xor(s2, 1);
          s2 += __shfl_xor(s2, 2);
          s2 += __shfl_xor(s2, 4);
          s2 += __shfl_xor(s2, 8);
          if (fr == 0) rss[w][i * 16 + fq * 4 + r] = s2;
        }
      __syncthreads();
#pragma unroll
      for (int i = 0; i < 4; i++)
#pragma unroll
        for (int r = 0; r < 4; r++) {
          int rl = i * 16 + fq * 4 + r;
          float tot = rss[w][rl] + rss[w ^ 1][rl];
          float sc = rsqrtf(tot * (1.f / 128.f) + EPSF);
          long row = m0 + wm + rl;
          long bb = row >> 11, ss = row & 2047;
          __bf16* base = Cb + ((((long)tt * 4 + bb) * 16 + hh) * 2048 + ss) * 128;
#pragma unroll
          for (int j = 0; j < 4; j++)
            base[wn + j * 16 + fr] = (__bf16)(acc[i][j][r] * sc);
        }
    } else {
#pragma unroll
      for (int i = 0; i < 4; i++)
#pragma unroll
        for (int r = 0; r < 4; r++) {
          long row = m0 + wm + i * 16 + fq * 4 + r;
          long bb = row >> 11, ss = row & 2047;
          __bf16* base = Vtb + ((bb * 16 + hh) * 128) * 2048 + ss;
#pragma unroll
          for (int j = 0; j < 4; j++)
            base[(long)(wn + j * 16 + fr) * 2048] = (__bf16)(acc[i][j][r]);
        }
    }
  }
}

// ---------------- flash attention v4: 512-thr block, 8 waves x 1 fragment ----
// grid = 512 blocks; qt = L>>6 (0..7), bh = (L&7)+8*((L>>3)&7).
// Block covers 128-row q-macro-tile qi (wave w owns rows qi*128+w*16..+15) and its
// causal mirror 15-qi, sequentially -> uniform 34 stages/block. K/V (64x128 / 128x64)
// staged once per stage via global_load_lds, shared by all 8 waves. 16 waves/CU.
__global__ __launch_bounds__(512) void attn(const __bf16* __restrict__ qkv,
                                            const __bf16* __restrict__ vt,
                                            __bf16* __restrict__ an) {
  __shared__ __bf16 Ks[64 * 128];   // [k row][128 e], 16B-blocks XOR-swizzled by (row&7)
  __shared__ __bf16 Vs[128 * 64];   // [e row][64 s], 16B-blocks XOR-swizzled by (row&7)
  __shared__ __bf16 plds[8][16 * 40];
  const int L = blockIdx.x;
  const int qt = L >> 6;                        // 0..7
  const int bh = (L & 7) + 8 * ((L >> 3) & 7);  // 0..63
  const int t = threadIdx.x;
  const int lane = t & 63, w = t >> 6;          // w = 0..7
  const int fr = lane & 15, fq = lane >> 4;
  const int swz = fr & 7;
  const __bf16* Q = qkv + (long)bh * 262144;
  const __bf16* Kbh = qkv + 16777216L + (long)bh * 262144;
  const __bf16* Vbh = vt + (long)bh * 262144;
  __bf16* pw = plds[w];
  const float sc2 = 0.08838834764831845f * 1.4426950408889634f;  // 1/sqrt(128)*log2(e)
  const float MFIX = 20.0f;  // |score*log2e/sqrt(hd)| <= 16.34 after rms-norm
  const int b = bh >> 4, h = bh & 15;

  // staging (512 threads, 2 calls each for K and V):
  // K call j: slot s=j*512+t -> row s>>4, 16B-blk (s&15)^((s>>4)&7); dest Ks[s*8]
  const __bf16* gK = Kbh + (long)(t >> 4) * 128 + ((t & 15) ^ ((t >> 4) & 7)) * 8;
  // V call j: slot s=j*512+t -> row s>>3, blk (s&7)^((s>>3)&7); dest Vs[s*8]
  const __bf16* gV = Vbh + (long)(t >> 3) * 2048 + ((t & 7) ^ ((t >> 3) & 7)) * 8;
  __bf16* lK = &Ks[t * 8];
  __bf16* lV = &Vs[t * 8];

#pragma unroll 1
  for (int side = 0; side < 2; side++) {
    const int qi = side ? (15 - qt) : qt;  // macro-tile 0..15
    const int q0 = qi * 128 + w * 16;      // this wave's 16 q rows
    const int cha = q0 >> 5;               // diagonal 32-chunk
    bf16x8 qf[4];
#pragma unroll
    for (int ec = 0; ec < 4; ec++)
      qf[ec] = *(const bf16x8*)(Q + (long)(q0 + fr) * 128 + ec * 32 + fq * 8);
    float lacc[4];
#pragma unroll
    for (int r = 0; r < 4; r++) lacc[r] = 0.f;
    f32x4 oacc[8];
#pragma unroll
    for (int e = 0; e < 8; e++)
#pragma unroll
      for (int c = 0; c < 4; c++) oacc[e][c] = 0.f;

    const int nst = 2 * qi + 2;
#pragma unroll 1
    for (int st = 0; st < nst; st++) {
      const int k0 = st * 64;
      gl_lds16(gK + (long)k0 * 128, lK);
      gl_lds16(gK + (long)(k0 + 32) * 128, lK + 4096);
      gl_lds16(gV + k0, lV);
      gl_lds16(gV + 64L * 2048 + k0, lV + 4096);
      __syncthreads();
#pragma unroll
      for (int half = 0; half < 2; half++) {
        const int k32 = k0 + half * 32;
        const int ch = k32 >> 5;
        if (ch <= cha) {  // wave-uniform causal skip
          f32x4 sa[2];
#pragma unroll
          for (int ct = 0; ct < 2; ct++)
#pragma unroll
            for (int c = 0; c < 4; c++) sa[ct][c] = 0.f;
#pragma unroll
          for (int ct = 0; ct < 2; ct++) {
#pragma unroll
            for (int ec = 0; ec < 4; ec++) {
              bf16x8 kf = *(const bf16x8*)(&Ks[(half * 32 + ct * 16 + fr) * 128 +
                                               ((ec * 4 + fq) ^ swz) * 8]);
              sa[ct] = __builtin_amdgcn_mfma_f32_16x16x32_bf16(qf[ec], kf, sa[ct], 0, 0, 0);
            }
          }
          if (ch == cha) {  // diagonal: masked
#pragma unroll
            for (int r = 0; r < 4; r++) {
              int qg = q0 + fq * 4 + r;
              float p0 = exp2f(((k32 + fr) <= qg) ? sa[0][r] * sc2 - MFIX : -1e30f);
              float p1 = exp2f(((k32 + 16 + fr) <= qg) ? sa[1][r] * sc2 - MFIX : -1e30f);
              lacc[r] += p0 + p1;
              pw[(fq * 4 + r) * 40 + fr] = (__bf16)p0;
              pw[(fq * 4 + r) * 40 + 16 + fr] = (__bf16)p1;
            }
          } else {  // compare-free fast path
#pragma unroll
            for (int r = 0; r < 4; r++) {
              float p0 = exp2f(__builtin_fmaf(sa[0][r], sc2, -MFIX));
              float p1 = exp2f(__builtin_fmaf(sa[1][r], sc2, -MFIX));
              lacc[r] += p0 + p1;
              pw[(fq * 4 + r) * 40 + fr] = (__bf16)p0;
              pw[(fq * 4 + r) * 40 + 16 + fr] = (__bf16)p1;
            }
          }
          // P: C-layout -> LDS -> A-layout (wave-synchronous)
          bf16x8 pa = *(const bf16x8*)(&pw[fr * 40 + fq * 8]);
#pragma unroll
          for (int e = 0; e < 8; e++) {
            bf16x8 vf = *(const bf16x8*)(&Vs[(e * 16 + fr) * 64 +
                                             ((half * 4 + fq) ^ swz) * 8]);
            oacc[e] = __builtin_amdgcn_mfma_f32_16x16x32_bf16(pa, vf, oacc[e], 0, 0, 0);
          }
        }
      }
      __syncthreads();
    }
    // epilogue: reduce l; /l + rms-norm + store
#pragma unroll
    for (int r = 0; r < 4; r++) {
      float ls = lacc[r];
      ls += __shfl_xor(ls, 1);
      ls += __shfl_xor(ls, 2);
      ls += __shfl_xor(ls, 4);
      ls += __shfl_xor(ls, 8);
      float inv = 1.0f / ls;
      float ssq = 0.f;
#pragma unroll
      for (int e = 0; e < 8; e++) { float v = oacc[e][r] * inv; ssq += v * v; }
      ssq += __shfl_xor(ssq, 1);
      ssq += __shfl_xor(ssq, 2);
      ssq += __shfl_xor(ssq, 4);
      ssq += __shfl_xor(ssq, 8);
      float rsc = rsqrtf(ssq * (1.f / 128.f) + EPSF) * inv;
      long s = q0 + fq * 4 + r;
      __bf16* dst = an + ((long)b * 2048 + s) * 2048 + h * 128;
#pragma unroll
      for (int e = 0; e < 8; e++) dst[e * 16 + fr] = (__bf16)(oacc[e][r] * rsc);
    }
  }
}

// ---------------- launch ----------------
extern "C" void kernel_launch(void* const* d_in, const int* in_sizes, int n_in,
                              void* d_out, int out_size, void* d_ws, size_t ws_size,
                              hipStream_t stream) {
  const float* x = (const float*)d_in[0];
  const float* w_in = (const float*)d_in[1];
  const float* w_out = (const float*)d_in[2];
  float* out = (float*)d_out;
  char* ws = (char*)d_ws;

  __bf16* w_in_n = (__bf16*)(ws);                      // 25165824 B
  __bf16* w_out_n = (__bf16*)(ws + 25165824);          // 8388608 B
  __bf16* xb = (__bf16*)(ws + 33554432);               // 33554432 B (aliased by a_n)
  __bf16* an = xb;
  __bf16* qkv = (__bf16*)(ws + 67108864);              // q,k used (v region unused)
  __bf16* vt = (__bf16*)(ws + 167772160);              // 33554432 B

  norm_w<<<8192, 256, 0, stream>>>(w_in, w_out, w_in_n, w_out_n);
  cast_x<<<8192, 256, 0, stream>>>(x, xb);
  gemm_bt<1><<<dim3(48, 64), 256, 0, stream>>>(xb, w_in_n, nullptr, qkv, vt, 8192, 6144, 2048);
  attn<<<512, 512, 0, stream>>>(qkv, vt, an);
  gemm_bt<0><<<dim3(16, 64), 256, 0, stream>>>(an, w_out_n, out, nullptr, nullptr, 8192, 2048, 2048);
}